// Round 6
// baseline (4972.862 us; speedup 1.0000x reference)
//
#include <hip/hip_runtime.h>
#include <math.h>
#include <stdint.h>

#define FMW 50
#define P_IMG 2500
#define CIN 512
#define NANCH 22500
#define BATCH 16
#define PRE 512
#define POST 128
#define NCHUNK 11             // 2048-elem chunks
#define NPAD (NCHUNK * 2048)  // 22528
#define AHALO 52
#define PXB 256               // block px tile
#define AW 360                // 52 + 256 + 52

typedef __attribute__((ext_vector_type(8))) short short8;
typedef __attribute__((ext_vector_type(16))) float f32x16;

union U4S8 { uint4 u; short8 s; };

__device__ __forceinline__ unsigned short f2bf(float x) {
    unsigned u = __float_as_uint(x);
    unsigned r = u + 0x7FFFu + ((u >> 16) & 1u);
    return (unsigned short)(r >> 16);
}
__device__ __forceinline__ float bf2f(unsigned short h) {
    return __uint_as_float(((unsigned)h) << 16);
}
__device__ __forceinline__ void gload_lds16(const void* g, void* l) {
    __builtin_amdgcn_global_load_lds(
        (const __attribute__((address_space(1))) void*)g,
        (__attribute__((address_space(3))) void*)l, 16, 0, 0);
}

// ---------------- K0: prepack w1 -> bf16 hi/lo MFMA-fragment order (V4, verified) ----
// layout: (pos*32+c)*32768 + NT*2048 + s*1024 + lane*16 ; NT in [0,16)
__global__ __launch_bounds__(256)
void k_prepack(const float* __restrict__ w1, char* __restrict__ w1pack) {
    __shared__ char sm[36864];
    const int t = threadIdx.x;
    const int co_g = blockIdx.x >> 5;
    const int c = blockIdx.x & 31;
#pragma unroll
    for (int k = 0; k < 4; ++k) {
        int pi = k * 256 + t;
        int oc_l = pi >> 4, ci_l = pi & 15;
        int oc = co_g * 64 + oc_l;
        int ci = c * 16 + ci_l;
        int NT2 = oc_l >> 5;
        int lane = (oc_l & 31) + ((ci_l >> 3) << 5);
        int j = ci_l & 7;
        const float* src = w1 + ((size_t)oc * 512 + ci) * 9;
#pragma unroll
        for (int pos = 0; pos < 9; ++pos) {
            float x = src[pos];
            unsigned short h = f2bf(x);
            unsigned short lo = f2bf(x - bf2f(h));
            *(unsigned short*)(sm + ((pos * 2) * 2 + NT2) * 1024 + lane * 16 + j * 2) = h;
            *(unsigned short*)(sm + ((pos * 2 + 1) * 2 + NT2) * 1024 + lane * 16 + j * 2) = lo;
        }
    }
    __syncthreads();
    const int s = (t >> 6) & 1, NT2 = t >> 7, l = t & 63;
#pragma unroll
    for (int pos = 0; pos < 9; ++pos) {
        uint4 v = *(const uint4*)(sm + ((pos * 2 + s) * 2 + NT2) * 1024 + l * 16);
        *(uint4*)(w1pack + (size_t)(pos * 32 + c) * 32768
                  + ((co_g * 2 + NT2) * 2 + s) * 1024 + l * 16) = v;
    }
}

// ---------------- K1: MFMA conv, oc-sliced (slot=blk&3 -> L2-resident B slice) -----
// block = 256 thr = 4 waves (w = px-row of 64); block tile 256 px x 128 oc;
// wave tile 64 px x 128 oc (mt=2, nt=4, 8 f32x16 accs).
__global__ __launch_bounds__(256, 3)
void k_conv_mfma(const float* __restrict__ fm, const char* __restrict__ w1pack,
                 const float* __restrict__ b1, const float* __restrict__ w2,
                 const float* __restrict__ w3, float* __restrict__ z) {
    // phase1: A hi [0,11520) | A lo [11520,23040) | Bb0 [23040,+8192) | Bb1 [31232,+8192)
    // phase2: SH[128 oc][33 px] f32 = 16896 @0 | W[45][128] f32 = 23040 @16896
    __shared__ __align__(16) char smem[39936];

    const int t = threadIdx.x;
    const int l = t & 63;
    const int w = t >> 6;                 // px-row 0..3
    const int lane31 = l & 31, lhalf = l >> 5;
    const int blk = blockIdx.x;
    const int slot = blk & 3;             // oc slice: [slot*128, slot*128+128)
    const int tid2 = blk >> 2;
    const int img = tid2 / 10;
    const int p0 = (tid2 % 10) * PXB;
    const int ocb = slot * 128;

    f32x16 acc[2][4];
#pragma unroll
    for (int mt = 0; mt < 2; ++mt)
#pragma unroll
        for (int nt = 0; nt < 4; ++nt)
#pragma unroll
            for (int g = 0; g < 16; ++g) acc[mt][nt][g] = 0.f;

    int xs[2];
#pragma unroll
    for (int mt = 0; mt < 2; ++mt) xs[mt] = (p0 + w * 64 + mt * 32 + lane31) % FMW;

    const int arb = (AHALO + w * 64 + lane31) * 32 + lhalf * 16;
    const size_t img_base = (size_t)img * CIN * P_IMG;
    const int DPOS[9] = {-51, -50, -49, -1, 0, 1, 49, 50, 51};

    char* Bb0 = smem + 23040;
    char* Bb1 = smem + 31232;

    auto stageA = [&](int c) {
#pragma unroll
        for (int r = 0; r < 6; ++r) {
            int flat = r * 256 + t;       // 360*4 = 1440 items
            if (flat < 1440) {
                int qq = flat & 3;
                int u = flat >> 2;
                int pw = p0 - AHALO + u;
                bool ok = (pw >= 0) && (pw < P_IMG);
                float v[4];
#pragma unroll
                for (int k = 0; k < 4; ++k)
                    v[k] = ok ? fm[img_base + (size_t)(c * 16 + qq * 4 + k) * P_IMG + pw] : 0.f;
                unsigned short h[4], lo[4];
#pragma unroll
                for (int k = 0; k < 4; ++k) {
                    h[k] = f2bf(v[k]);
                    lo[k] = f2bf(v[k] - bf2f(h[k]));
                }
                uint2 hu, lu;
                hu.x = h[0] | ((unsigned)h[1] << 16);  hu.y = h[2] | ((unsigned)h[3] << 16);
                lu.x = lo[0] | ((unsigned)lo[1] << 16); lu.y = lo[2] | ((unsigned)lo[3] << 16);
                *(uint2*)(smem + u * 32 + qq * 8) = hu;
                *(uint2*)(smem + 11520 + u * 32 + qq * 8) = lu;
            }
        }
    };

    // stage 8KB B slice for iteration kk: 8 chunks of 1KB, 2 per wave
    auto stageB = [&](int kk) {
        int c = kk / 9, pos = kk % 9;
        const char* src = w1pack + (size_t)(pos * 32 + c) * 32768 + (size_t)slot * 8192;
        char* dst = (kk & 1) ? Bb1 : Bb0;
#pragma unroll
        for (int j = 0; j < 2; ++j) {
            int ch = w * 2 + j;
            gload_lds16(src + ch * 1024 + l * 16, dst + ch * 1024);
        }
    };

    stageB(0);
    stageA(0);
    __syncthreads();

    for (int kk = 0; kk < 288; ++kk) {
        const int c = kk / 9, pos = kk % 9;
        if (kk + 1 < 288) stageB(kk + 1);

        const int dpos = DPOS[pos];
        const int dx = pos % 3 - 1;
        U4S8 ah[2], al[2];
        const char* ap = smem + arb + dpos * 32;
#pragma unroll
        for (int mt = 0; mt < 2; ++mt) {
            ah[mt].u = *(const uint4*)(ap + mt * 1024);
            al[mt].u = *(const uint4*)(ap + 11520 + mt * 1024);
            bool xok = (dx == 0) || (dx < 0 ? (xs[mt] > 0) : (xs[mt] < FMW - 1));
            if (!xok) {
                ah[mt].u.x = 0; ah[mt].u.y = 0; ah[mt].u.z = 0; ah[mt].u.w = 0;
                al[mt].u.x = 0; al[mt].u.y = 0; al[mt].u.z = 0; al[mt].u.w = 0;
            }
        }
        const char* bp = ((kk & 1) ? Bb1 : Bb0) + l * 16;
#pragma unroll
        for (int nt = 0; nt < 4; ++nt) {
            U4S8 vh, vl;
            vh.u = *(const uint4*)(bp + nt * 2048);
            vl.u = *(const uint4*)(bp + nt * 2048 + 1024);
#pragma unroll
            for (int mt = 0; mt < 2; ++mt) {
                acc[mt][nt] = __builtin_amdgcn_mfma_f32_32x32x16_bf16(ah[mt].s, vh.s, acc[mt][nt], 0, 0, 0);
                acc[mt][nt] = __builtin_amdgcn_mfma_f32_32x32x16_bf16(al[mt].s, vh.s, acc[mt][nt], 0, 0, 0);
                acc[mt][nt] = __builtin_amdgcn_mfma_f32_32x32x16_bf16(ah[mt].s, vl.s, acc[mt][nt], 0, 0, 0);
            }
        }

        if (pos == 8 && c < 31) {
            __syncthreads();
            stageA(c + 1);
        }
        __syncthreads();
    }

    // ---------------- partial 1x1 epilogue: atomicAdd into z[(img*2500+p)*45+o] ----
    float* SH = (float*)smem;              // [128 oc][33 px]
    float* W  = (float*)(smem + 16896);    // [45][128]
    float b1v[4];
#pragma unroll
    for (int nt = 0; nt < 4; ++nt) b1v[nt] = b1[ocb + nt * 32 + lane31];

    // stage W (45 x 128 ci-slice)
#pragma unroll
    for (int i = 0; i < 23; ++i) {
        int e = i * 256 + t;
        if (e < 5760) {
            int o = e >> 7, cl = e & 127;
            W[o * 128 + cl] = (o < 9) ? w2[o * 512 + ocb + cl]
                                      : w3[(o - 9) * 512 + ocb + cl];
        }
    }

    const int px_l = t & 31;
    const int og = t >> 5;                 // 0..7, outputs o = og*6+m
    for (int rd = 0; rd < 8; ++rd) {
        __syncthreads();
        if (w == (rd >> 1)) {
            int mt = rd & 1;
#pragma unroll
            for (int nt = 0; nt < 4; ++nt) {
                int oc_l = nt * 32 + lane31;
#pragma unroll
                for (int g = 0; g < 16; ++g) {
                    int row = (g & 3) + 8 * (g >> 2) + 4 * lhalf;
                    SH[oc_l * 33 + row] = fmaxf(acc[mt][nt][g] + b1v[nt], 0.f);
                }
            }
        }
        __syncthreads();
        int p = p0 + rd * 32 + px_l;
        if (p < P_IMG) {
            float s[6];
#pragma unroll
            for (int m = 0; m < 6; ++m) s[m] = 0.f;
            for (int cl = 0; cl < 128; ++cl) {
                float sv = SH[cl * 33 + px_l];
#pragma unroll
                for (int m = 0; m < 6; ++m) {
                    int o = og * 6 + m;
                    if (o < 45) s[m] = fmaf(sv, W[o * 128 + cl], s[m]);
                }
            }
            float* zp = z + ((size_t)img * P_IMG + p) * 45;
#pragma unroll
            for (int m = 0; m < 6; ++m) {
                int o = og * 6 + m;
                if (o < 45) atomicAdd(zp + o, s[m]);
            }
        }
    }
}

// ---------------- K1b: scores -> sorted keys ----------------
__global__ __launch_bounds__(256)
void k_scores(const float* __restrict__ z, const float* __restrict__ b2,
              unsigned long long* __restrict__ keys) {
    int id = blockIdx.x * 256 + threadIdx.x;     // 16 * 22500
    if (id >= BATCH * NANCH) return;
    int img = id / NANCH;
    int n = id - img * NANCH;
    int px = n / 9, o = n - px * 9;
    float zv = z[((size_t)img * P_IMG + px) * 45 + o] + b2[o];
    float s = (zv >= 0.f) ? (1.f / (1.f + expf(-zv)))
                          : (expf(zv) / (1.f + expf(zv)));
    unsigned long long key =
        ((unsigned long long)__float_as_uint(s) << 32) |
        (unsigned long long)(0xFFFFFFFFu - (unsigned)n);
    keys[(size_t)img * NPAD + n] = key;
}

// ---------------- K2: bitonic sort each 2048-chunk descending (pad-guarded) -------
__global__ __launch_bounds__(512)
void k_sort_chunks(unsigned long long* __restrict__ keys) {
    __shared__ unsigned long long sk[2048];
    const int t = threadIdx.x;
    const int img = blockIdx.x / NCHUNK;
    const int ch = blockIdx.x % NCHUNK;
    const size_t base = (size_t)img * NPAD + ch * 2048;
#pragma unroll
    for (int i = 0; i < 4; ++i) {
        int idx = i * 512 + t;
        sk[idx] = (ch * 2048 + idx < NANCH) ? keys[base + idx] : 0ull;
    }
    for (int k = 2; k <= 2048; k <<= 1)
        for (int j = k >> 1; j > 0; j >>= 1) {
            __syncthreads();
            for (int i = t; i < 2048; i += 512) {
                int lx = i ^ j;
                if (lx > i) {
                    unsigned long long a = sk[i], b = sk[lx];
                    bool desc = ((i & k) == 0);
                    if (desc ? (a < b) : (a > b)) { sk[i] = b; sk[lx] = a; }
                }
            }
        }
    __syncthreads();
#pragma unroll
    for (int i = 0; i < 4; ++i) {
        int idx = i * 512 + t;
        keys[base + idx] = sk[idx];
    }
}

// ---------------- K3: merge top-512, decode, NMS, top-128 ----------------
__global__ __launch_bounds__(256)
void k_nms(const unsigned long long* __restrict__ keys, const float* __restrict__ z,
           const float* __restrict__ b3, float* __restrict__ out) {
    __shared__ unsigned long long top[512];
    __shared__ unsigned long long chk[512];
    __shared__ float bx1[512], by1[512], bx2[512], by2[512], bar[512], bsc[512];
    __shared__ int keep[512];

    const int t = threadIdx.x;
    const int img = blockIdx.x;
    const size_t kbase = (size_t)img * NPAD;

    top[t] = keys[kbase + t];
    top[t + 256] = keys[kbase + t + 256];

    for (int c = 1; c < NCHUNK; ++c) {      // each 2048-chunk sorted: first 512 suffice
        __syncthreads();
        chk[t] = keys[kbase + c * 2048 + t];
        chk[t + 256] = keys[kbase + c * 2048 + t + 256];
        __syncthreads();
        for (int i = t; i < 512; i += 256) {
            unsigned long long a = top[i], b = chk[511 - i];
            top[i] = (a > b) ? a : b;
        }
        for (int j = 256; j > 0; j >>= 1) {
            __syncthreads();
            int i = ((t & ~(j - 1)) << 1) | (t & (j - 1));
            unsigned long long a = top[i], b = top[i + j];
            if (a < b) { top[i] = b; top[i + j] = a; }
        }
    }
    __syncthreads();

    for (int i = t; i < 512; i += 256) {
        unsigned long long key = top[i];
        float s = __uint_as_float((unsigned)(key >> 32));
        unsigned id = 0xFFFFFFFFu - (unsigned)(key & 0xFFFFFFFFull);
        float x1 = 0.f, y1 = 0.f, x2 = 0.f, y2 = 0.f;
        bool valid = false;
        if (key != 0ull && id < (unsigned)NANCH) {
            int p = id / 9, a = id - p * 9;
            int gy = p / FMW, gx = p - gy * FMW;
            const double SS[3] = {32.0, 64.0, 128.0};
            const double RR[3] = {0.5, 1.0, 2.0};
            double sq = sqrt(RR[a % 3]);
            float wa32 = (float)(SS[a / 3] / sq);
            float ha32 = (float)(SS[a / 3] * sq);
            double cx = ((double)gx + 0.5) * 16.0;
            double cy = ((double)gy + 0.5) * 16.0;
            float ax1 = (float)(cx - (double)(wa32 * 0.5f));
            float ay1 = (float)(cy - (double)(ha32 * 0.5f));
            float ax2 = (float)(cx + (double)(wa32 * 0.5f));
            float ay2 = (float)(cy + (double)(ha32 * 0.5f));
            float aw = ax2 - ax1, ah2 = ay2 - ay1;
            float acx = ax1 + 0.5f * aw, acy = ay1 + 0.5f * ah2;
            const float* zp = z + ((size_t)img * P_IMG + p) * 45 + 9 + a * 4;
            float ox = zp[0] + b3[a * 4 + 0];
            float oy = zp[1] + b3[a * 4 + 1];
            float ow = zp[2] + b3[a * 4 + 2];
            float oh = zp[3] + b3[a * 4 + 3];
            float px = acx + ox * aw;
            float py = acy + oy * ah2;
            float pw = aw * expf(ow);
            float ph = ah2 * expf(oh);
            x1 = fminf(fmaxf(px - 0.5f * pw, 0.f), 800.f);
            y1 = fminf(fmaxf(py - 0.5f * ph, 0.f), 800.f);
            x2 = fminf(fmaxf(px + 0.5f * pw, 0.f), 800.f);
            y2 = fminf(fmaxf(py + 0.5f * ph, 0.f), 800.f);
            float ww = x2 - x1, hh = y2 - y1;
            valid = (ww >= 1e-3f) && (hh >= 1e-3f) && (s >= 0.5f);
        }
        bx1[i] = x1; by1[i] = y1; bx2[i] = x2; by2[i] = y2;
        bar[i] = (x2 - x1) * (y2 - y1);
        bsc[i] = s;
        keep[i] = valid ? 1 : 0;
    }
    __syncthreads();

    for (int i = 0; i < PRE - 1; ++i) {
        __syncthreads();
        if (keep[i] == 0) continue;
        float xi1 = bx1[i], yi1 = by1[i], xi2 = bx2[i], yi2 = by2[i], ai = bar[i];
        for (int j = i + 1 + t; j < PRE; j += 256) {
            if (keep[j]) {
                float lx = fmaxf(xi1, bx1[j]);
                float ly = fmaxf(yi1, by1[j]);
                float rx = fminf(xi2, bx2[j]);
                float ry = fminf(yi2, by2[j]);
                float iw = fmaxf(rx - lx, 0.f);
                float ih = fmaxf(ry - ly, 0.f);
                float inter = iw * ih;
                float iou = inter / (ai + bar[j] - inter + 1e-9f);
                if (iou > 0.7f) keep[j] = 0;
            }
        }
    }
    __syncthreads();

    for (int i = t; i < 512; i += 256) {
        float m = keep[i] ? bsc[i] : -1.0f;
        unsigned u = __float_as_uint(m);
        u = (u & 0x80000000u) ? ~u : (u | 0x80000000u);
        chk[i] = ((unsigned long long)u << 32) | (unsigned long long)(511 - i);
    }
    for (int k = 2; k <= 512; k <<= 1)
        for (int j = k >> 1; j > 0; j >>= 1) {
            __syncthreads();
            for (int i = t; i < 512; i += 256) {
                int lx = i ^ j;
                if (lx > i) {
                    unsigned long long a = chk[i], b = chk[lx];
                    bool desc = ((i & k) == 0);
                    if (desc ? (a < b) : (a > b)) { chk[i] = b; chk[lx] = a; }
                }
            }
        }
    __syncthreads();

    if (t < POST) {
        unsigned long long key = chk[t];
        int slot = 511 - (int)(key & 0xFFFFFFFFull);
        float m = keep[slot] ? bsc[slot] : -1.0f;
        bool ok = (m >= 0.5f);
        float* ob = out + ((size_t)img * POST + t) * 4;
        ob[0] = ok ? bx1[slot] : 0.f;
        ob[1] = ok ? by1[slot] : 0.f;
        ob[2] = ok ? bx2[slot] : 0.f;
        ob[3] = ok ? by2[slot] : 0.f;
        out[(size_t)BATCH * POST * 4 + img * POST + t] = ok ? m : 0.f;
    }
}

// ---------------- launcher ----------------
extern "C" void kernel_launch(void* const* d_in, const int* in_sizes, int n_in,
                              void* d_out, int out_size, void* d_ws, size_t ws_size,
                              hipStream_t stream) {
    const float* fm = (const float*)d_in[0];
    const float* w1 = (const float*)d_in[1];
    const float* b1 = (const float*)d_in[2];
    const float* w2 = (const float*)d_in[3];
    const float* b2 = (const float*)d_in[4];
    const float* w3 = (const float*)d_in[5];
    const float* b3 = (const float*)d_in[6];
    float* out = (float*)d_out;

    char* ws = (char*)d_ws;
    // ws layout (peak 16,637,184 B <= proven 18,087,936):
    //   w1pack @0        (9,437,184 B)  -- consumed by k_conv, then dead
    //   z      @0x900000 (7,200,000 B)  -- 16*2500*45 f32
    //   keys   @0        (2,883,584 B)  -- OVERLAYS w1pack; written by k_scores
    //                                      (stream-ordered after k_conv)
    char* w1pack = ws;
    float* z = (float*)(ws + 0x900000);
    unsigned long long* keys = (unsigned long long*)ws;

    (void)hipMemsetAsync(z, 0, (size_t)BATCH * P_IMG * 45 * sizeof(float), stream);
    k_prepack<<<256, 256, 0, stream>>>(w1, w1pack);
    k_conv_mfma<<<BATCH * 10 * 4, 256, 0, stream>>>(fm, w1pack, b1, w2, w3, z);
    k_scores<<<(BATCH * NANCH + 255) / 256, 256, 0, stream>>>(z, b2, keys);
    k_sort_chunks<<<BATCH * NCHUNK, 512, 0, stream>>>(keys);
    k_nms<<<BATCH, 256, 0, stream>>>(keys, z, b3, out);
}

// Round 7
// 1552.992 us; speedup vs baseline: 3.2021x; 3.2021x over previous
//
#include <hip/hip_runtime.h>
#include <math.h>
#include <stdint.h>

#define FMW 50
#define P_IMG 2500
#define CIN 512
#define NANCH 22500
#define BATCH 16
#define PRE 512
#define POST 128
#define NCHUNK 11             // 2048-elem chunks
#define NPAD (NCHUNK * 2048)  // 22528
#define AHALO 52
#define PXB 128               // block px tile
#define AW 232                // 52 + 128 + 52

typedef __attribute__((ext_vector_type(8))) short short8;
typedef __attribute__((ext_vector_type(16))) float f32x16;

union U4S8 { uint4 u; short8 s; };

__device__ __forceinline__ unsigned short f2bf(float x) {
    unsigned u = __float_as_uint(x);
    unsigned r = u + 0x7FFFu + ((u >> 16) & 1u);
    return (unsigned short)(r >> 16);
}
__device__ __forceinline__ float bf2f(unsigned short h) {
    return __uint_as_float(((unsigned)h) << 16);
}
__device__ __forceinline__ void gload_lds16(const void* g, void* l) {
    __builtin_amdgcn_global_load_lds(
        (const __attribute__((address_space(1))) void*)g,
        (__attribute__((address_space(3))) void*)l, 16, 0, 0);
}

// ---------------- K0: prepack w1 -> bf16 hi/lo MFMA-fragment order (verified) ----
// layout: (pos*32+c)*32768 + NT*2048 + s*1024 + lane*16 ; NT in [0,16)
__global__ __launch_bounds__(256)
void k_prepack(const float* __restrict__ w1, char* __restrict__ w1pack) {
    __shared__ char sm[36864];
    const int t = threadIdx.x;
    const int co_g = blockIdx.x >> 5;
    const int c = blockIdx.x & 31;
#pragma unroll
    for (int k = 0; k < 4; ++k) {
        int pi = k * 256 + t;
        int oc_l = pi >> 4, ci_l = pi & 15;
        int oc = co_g * 64 + oc_l;
        int ci = c * 16 + ci_l;
        int NT2 = oc_l >> 5;
        int lane = (oc_l & 31) + ((ci_l >> 3) << 5);
        int j = ci_l & 7;
        const float* src = w1 + ((size_t)oc * 512 + ci) * 9;
#pragma unroll
        for (int pos = 0; pos < 9; ++pos) {
            float x = src[pos];
            unsigned short h = f2bf(x);
            unsigned short lo = f2bf(x - bf2f(h));
            *(unsigned short*)(sm + ((pos * 2) * 2 + NT2) * 1024 + lane * 16 + j * 2) = h;
            *(unsigned short*)(sm + ((pos * 2 + 1) * 2 + NT2) * 1024 + lane * 16 + j * 2) = lo;
        }
    }
    __syncthreads();
    const int s = (t >> 6) & 1, NT2 = t >> 7, l = t & 63;
#pragma unroll
    for (int pos = 0; pos < 9; ++pos) {
        uint4 v = *(const uint4*)(sm + ((pos * 2 + s) * 2 + NT2) * 1024 + l * 16);
        *(uint4*)(w1pack + (size_t)(pos * 32 + c) * 32768
                  + ((co_g * 2 + NT2) * 2 + s) * 1024 + l * 16) = v;
    }
}

// ---------------- K1: MFMA conv, small wave tile for occupancy ----------------
// block = 256 thr = 4 waves in 2x2 (r = px-row of 64, q = oc-col of 64);
// block tile 128 px x 128 oc (slot = blk&3 -> oc slice); wave tile 64x64
// (acc = 4 x f32x16 = 64 AGPRs -> total regs/wave ~170-190 -> ~3 blocks/CU).
__global__ __launch_bounds__(256)
void k_conv_mfma(const float* __restrict__ fm, const char* __restrict__ w1pack,
                 const float* __restrict__ b1, const float* __restrict__ w2,
                 const float* __restrict__ w3, float* __restrict__ z) {
    // phase1: A hi [0,7424) | A lo [7424,14848) | Bb0 @14848 (8192) | Bb1 @23040 (8192)
    // phase2: SH[128 oc][33 px] f32 = 16896 @0 | W[45][128] f32 = 23040 @16896
    __shared__ __align__(16) char smem[39936];

    const int t = threadIdx.x;
    const int l = t & 63;
    const int w = t >> 6;                 // 0..3
    const int r = w >> 1;                 // px-row 0..1 (64 px each)
    const int q = w & 1;                  // oc-col 0..1 (64 oc each)
    const int lane31 = l & 31, lhalf = l >> 5;
    const int blk = blockIdx.x;
    const int slot = blk & 3;             // oc slice [slot*128, slot*128+128)
    const int tid2 = blk >> 2;
    const int img = tid2 / 20;
    const int p0 = (tid2 % 20) * PXB;
    const int ocb = slot * 128;

    f32x16 acc[2][2];
#pragma unroll
    for (int mt = 0; mt < 2; ++mt)
#pragma unroll
        for (int nt = 0; nt < 2; ++nt)
#pragma unroll
            for (int g = 0; g < 16; ++g) acc[mt][nt][g] = 0.f;

    int xs[2];
#pragma unroll
    for (int mt = 0; mt < 2; ++mt) xs[mt] = (p0 + r * 64 + mt * 32 + lane31) % FMW;

    const int arb = (AHALO + r * 64 + lane31) * 32 + lhalf * 16;
    const size_t img_base = (size_t)img * CIN * P_IMG;
    const int DPOS[9] = {-51, -50, -49, -1, 0, 1, 49, 50, 51};

    char* Bb0 = smem + 14848;
    char* Bb1 = smem + 23040;

    auto stageA = [&](int c) {
#pragma unroll
        for (int rr = 0; rr < 4; ++rr) {
            int flat = rr * 256 + t;      // 232*4 = 928 items
            if (flat < 928) {
                int qq = flat & 3;
                int u = flat >> 2;
                int pw = p0 - AHALO + u;
                bool ok = (pw >= 0) && (pw < P_IMG);
                float v[4];
#pragma unroll
                for (int k = 0; k < 4; ++k)
                    v[k] = ok ? fm[img_base + (size_t)(c * 16 + qq * 4 + k) * P_IMG + pw] : 0.f;
                unsigned short h[4], lo[4];
#pragma unroll
                for (int k = 0; k < 4; ++k) {
                    h[k] = f2bf(v[k]);
                    lo[k] = f2bf(v[k] - bf2f(h[k]));
                }
                uint2 hu, lu;
                hu.x = h[0] | ((unsigned)h[1] << 16);  hu.y = h[2] | ((unsigned)h[3] << 16);
                lu.x = lo[0] | ((unsigned)lo[1] << 16); lu.y = lo[2] | ((unsigned)lo[3] << 16);
                *(uint2*)(smem + u * 32 + qq * 8) = hu;
                *(uint2*)(smem + 7424 + u * 32 + qq * 8) = lu;
            }
        }
    };

    // stage 8KB B slice for iteration kk: 8 chunks of 1KB, 2 per wave
    auto stageB = [&](int kk) {
        int c = kk / 9, pos = kk % 9;
        const char* src = w1pack + (size_t)(pos * 32 + c) * 32768 + (size_t)slot * 8192;
        char* dst = (kk & 1) ? Bb1 : Bb0;
#pragma unroll
        for (int j = 0; j < 2; ++j) {
            int ch = w * 2 + j;
            gload_lds16(src + ch * 1024 + l * 16, dst + ch * 1024);
        }
    };

    stageB(0);
    stageA(0);
    __syncthreads();

    for (int kk = 0; kk < 288; ++kk) {
        const int c = kk / 9, pos = kk % 9;
        if (kk + 1 < 288) stageB(kk + 1);

        const int dpos = DPOS[pos];
        const int dx = pos % 3 - 1;
        U4S8 ah[2], al[2];
        const char* ap = smem + arb + dpos * 32;
#pragma unroll
        for (int mt = 0; mt < 2; ++mt) {
            ah[mt].u = *(const uint4*)(ap + mt * 1024);
            al[mt].u = *(const uint4*)(ap + 7424 + mt * 1024);
            bool xok = (dx == 0) || (dx < 0 ? (xs[mt] > 0) : (xs[mt] < FMW - 1));
            if (!xok) {
                ah[mt].u.x = 0; ah[mt].u.y = 0; ah[mt].u.z = 0; ah[mt].u.w = 0;
                al[mt].u.x = 0; al[mt].u.y = 0; al[mt].u.z = 0; al[mt].u.w = 0;
            }
        }
        const char* bp = ((kk & 1) ? Bb1 : Bb0) + q * 4096 + l * 16;
#pragma unroll
        for (int nt = 0; nt < 2; ++nt) {
            U4S8 vh, vl;
            vh.u = *(const uint4*)(bp + nt * 2048);
            vl.u = *(const uint4*)(bp + nt * 2048 + 1024);
#pragma unroll
            for (int mt = 0; mt < 2; ++mt) {
                acc[mt][nt] = __builtin_amdgcn_mfma_f32_32x32x16_bf16(ah[mt].s, vh.s, acc[mt][nt], 0, 0, 0);
                acc[mt][nt] = __builtin_amdgcn_mfma_f32_32x32x16_bf16(al[mt].s, vh.s, acc[mt][nt], 0, 0, 0);
                acc[mt][nt] = __builtin_amdgcn_mfma_f32_32x32x16_bf16(ah[mt].s, vl.s, acc[mt][nt], 0, 0, 0);
            }
        }

        if (pos == 8 && c < 31) {
            __syncthreads();
            stageA(c + 1);
        }
        __syncthreads();
    }

    // ---------------- partial 1x1 epilogue: atomicAdd into z[(img*2500+p)*45+o] ----
    float* SH = (float*)smem;              // [128 oc][33 px]
    float* W  = (float*)(smem + 16896);    // [45][128]
    float b1v[2];
#pragma unroll
    for (int nt = 0; nt < 2; ++nt) b1v[nt] = b1[ocb + q * 64 + nt * 32 + lane31];

    // stage W (45 x 128 ci-slice)
#pragma unroll
    for (int i = 0; i < 23; ++i) {
        int e = i * 256 + t;
        if (e < 5760) {
            int o = e >> 7, cl = e & 127;
            W[o * 128 + cl] = (o < 9) ? w2[o * 512 + ocb + cl]
                                      : w3[(o - 9) * 512 + ocb + cl];
        }
    }

    const int px_l = t & 31;
    const int og = t >> 5;                 // 0..7, outputs o = og*6+m
    for (int rd = 0; rd < 4; ++rd) {       // 4 rounds of 32 px
        __syncthreads();
        if (r == (rd >> 1)) {              // both q-waves of this row write
            int mt = rd & 1;
#pragma unroll
            for (int nt = 0; nt < 2; ++nt) {
                int oc_l = q * 64 + nt * 32 + lane31;
#pragma unroll
                for (int g = 0; g < 16; ++g) {
                    int row = (g & 3) + 8 * (g >> 2) + 4 * lhalf;
                    SH[oc_l * 33 + row] = fmaxf(acc[mt][nt][g] + b1v[nt], 0.f);
                }
            }
        }
        __syncthreads();
        int p = p0 + rd * 32 + px_l;
        if (p < P_IMG) {
            float s[6];
#pragma unroll
            for (int m = 0; m < 6; ++m) s[m] = 0.f;
            for (int cl = 0; cl < 128; ++cl) {
                float sv = SH[cl * 33 + px_l];
#pragma unroll
                for (int m = 0; m < 6; ++m) {
                    int o = og * 6 + m;
                    if (o < 45) s[m] = fmaf(sv, W[o * 128 + cl], s[m]);
                }
            }
            float* zp = z + ((size_t)img * P_IMG + p) * 45;
#pragma unroll
            for (int m = 0; m < 6; ++m) {
                int o = og * 6 + m;
                if (o < 45) atomicAdd(zp + o, s[m]);
            }
        }
    }
}

// ---------------- K1b: scores -> keys ----------------
__global__ __launch_bounds__(256)
void k_scores(const float* __restrict__ z, const float* __restrict__ b2,
              unsigned long long* __restrict__ keys) {
    int id = blockIdx.x * 256 + threadIdx.x;     // 16 * 22500
    if (id >= BATCH * NANCH) return;
    int img = id / NANCH;
    int n = id - img * NANCH;
    int px = n / 9, o = n - px * 9;
    float zv = z[((size_t)img * P_IMG + px) * 45 + o] + b2[o];
    float s = (zv >= 0.f) ? (1.f / (1.f + expf(-zv)))
                          : (expf(zv) / (1.f + expf(zv)));
    unsigned long long key =
        ((unsigned long long)__float_as_uint(s) << 32) |
        (unsigned long long)(0xFFFFFFFFu - (unsigned)n);
    keys[(size_t)img * NPAD + n] = key;
}

// ---------------- K2: bitonic sort each 2048-chunk descending (pad-guarded) -------
__global__ __launch_bounds__(512)
void k_sort_chunks(unsigned long long* __restrict__ keys) {
    __shared__ unsigned long long sk[2048];
    const int t = threadIdx.x;
    const int img = blockIdx.x / NCHUNK;
    const int ch = blockIdx.x % NCHUNK;
    const size_t base = (size_t)img * NPAD + ch * 2048;
#pragma unroll
    for (int i = 0; i < 4; ++i) {
        int idx = i * 512 + t;
        sk[idx] = (ch * 2048 + idx < NANCH) ? keys[base + idx] : 0ull;
    }
    for (int k = 2; k <= 2048; k <<= 1)
        for (int j = k >> 1; j > 0; j >>= 1) {
            __syncthreads();
            for (int i = t; i < 2048; i += 512) {
                int lx = i ^ j;
                if (lx > i) {
                    unsigned long long a = sk[i], b = sk[lx];
                    bool desc = ((i & k) == 0);
                    if (desc ? (a < b) : (a > b)) { sk[i] = b; sk[lx] = a; }
                }
            }
        }
    __syncthreads();
#pragma unroll
    for (int i = 0; i < 4; ++i) {
        int idx = i * 512 + t;
        keys[base + idx] = sk[idx];
    }
}

// ---------------- K3: merge top-512, decode, NMS, top-128 (verified) ----------------
__global__ __launch_bounds__(256)
void k_nms(const unsigned long long* __restrict__ keys, const float* __restrict__ z,
           const float* __restrict__ b3, float* __restrict__ out) {
    __shared__ unsigned long long top[512];
    __shared__ unsigned long long chk[512];
    __shared__ float bx1[512], by1[512], bx2[512], by2[512], bar[512], bsc[512];
    __shared__ int keep[512];

    const int t = threadIdx.x;
    const int img = blockIdx.x;
    const size_t kbase = (size_t)img * NPAD;

    top[t] = keys[kbase + t];
    top[t + 256] = keys[kbase + t + 256];

    for (int c = 1; c < NCHUNK; ++c) {
        __syncthreads();
        chk[t] = keys[kbase + c * 2048 + t];
        chk[t + 256] = keys[kbase + c * 2048 + t + 256];
        __syncthreads();
        for (int i = t; i < 512; i += 256) {
            unsigned long long a = top[i], b = chk[511 - i];
            top[i] = (a > b) ? a : b;
        }
        for (int j = 256; j > 0; j >>= 1) {
            __syncthreads();
            int i = ((t & ~(j - 1)) << 1) | (t & (j - 1));
            unsigned long long a = top[i], b = top[i + j];
            if (a < b) { top[i] = b; top[i + j] = a; }
        }
    }
    __syncthreads();

    for (int i = t; i < 512; i += 256) {
        unsigned long long key = top[i];
        float s = __uint_as_float((unsigned)(key >> 32));
        unsigned id = 0xFFFFFFFFu - (unsigned)(key & 0xFFFFFFFFull);
        float x1 = 0.f, y1 = 0.f, x2 = 0.f, y2 = 0.f;
        bool valid = false;
        if (key != 0ull && id < (unsigned)NANCH) {
            int p = id / 9, a = id - p * 9;
            int gy = p / FMW, gx = p - gy * FMW;
            const double SS[3] = {32.0, 64.0, 128.0};
            const double RR[3] = {0.5, 1.0, 2.0};
            double sq = sqrt(RR[a % 3]);
            float wa32 = (float)(SS[a / 3] / sq);
            float ha32 = (float)(SS[a / 3] * sq);
            double cx = ((double)gx + 0.5) * 16.0;
            double cy = ((double)gy + 0.5) * 16.0;
            float ax1 = (float)(cx - (double)(wa32 * 0.5f));
            float ay1 = (float)(cy - (double)(ha32 * 0.5f));
            float ax2 = (float)(cx + (double)(wa32 * 0.5f));
            float ay2 = (float)(cy + (double)(ha32 * 0.5f));
            float aw = ax2 - ax1, ah2 = ay2 - ay1;
            float acx = ax1 + 0.5f * aw, acy = ay1 + 0.5f * ah2;
            const float* zp = z + ((size_t)img * P_IMG + p) * 45 + 9 + a * 4;
            float ox = zp[0] + b3[a * 4 + 0];
            float oy = zp[1] + b3[a * 4 + 1];
            float ow = zp[2] + b3[a * 4 + 2];
            float oh = zp[3] + b3[a * 4 + 3];
            float px = acx + ox * aw;
            float py = acy + oy * ah2;
            float pw = aw * expf(ow);
            float ph = ah2 * expf(oh);
            x1 = fminf(fmaxf(px - 0.5f * pw, 0.f), 800.f);
            y1 = fminf(fmaxf(py - 0.5f * ph, 0.f), 800.f);
            x2 = fminf(fmaxf(px + 0.5f * pw, 0.f), 800.f);
            y2 = fminf(fmaxf(py + 0.5f * ph, 0.f), 800.f);
            float ww = x2 - x1, hh = y2 - y1;
            valid = (ww >= 1e-3f) && (hh >= 1e-3f) && (s >= 0.5f);
        }
        bx1[i] = x1; by1[i] = y1; bx2[i] = x2; by2[i] = y2;
        bar[i] = (x2 - x1) * (y2 - y1);
        bsc[i] = s;
        keep[i] = valid ? 1 : 0;
    }
    __syncthreads();

    for (int i = 0; i < PRE - 1; ++i) {
        __syncthreads();
        if (keep[i] == 0) continue;
        float xi1 = bx1[i], yi1 = by1[i], xi2 = bx2[i], yi2 = by2[i], ai = bar[i];
        for (int j = i + 1 + t; j < PRE; j += 256) {
            if (keep[j]) {
                float lx = fmaxf(xi1, bx1[j]);
                float ly = fmaxf(yi1, by1[j]);
                float rx = fminf(xi2, bx2[j]);
                float ry = fminf(yi2, by2[j]);
                float iw = fmaxf(rx - lx, 0.f);
                float ih = fmaxf(ry - ly, 0.f);
                float inter = iw * ih;
                float iou = inter / (ai + bar[j] - inter + 1e-9f);
                if (iou > 0.7f) keep[j] = 0;
            }
        }
    }
    __syncthreads();

    for (int i = t; i < 512; i += 256) {
        float m = keep[i] ? bsc[i] : -1.0f;
        unsigned u = __float_as_uint(m);
        u = (u & 0x80000000u) ? ~u : (u | 0x80000000u);
        chk[i] = ((unsigned long long)u << 32) | (unsigned long long)(511 - i);
    }
    for (int k = 2; k <= 512; k <<= 1)
        for (int j = k >> 1; j > 0; j >>= 1) {
            __syncthreads();
            for (int i = t; i < 512; i += 256) {
                int lx = i ^ j;
                if (lx > i) {
                    unsigned long long a = chk[i], b = chk[lx];
                    bool desc = ((i & k) == 0);
                    if (desc ? (a < b) : (a > b)) { chk[i] = b; chk[lx] = a; }
                }
            }
        }
    __syncthreads();

    if (t < POST) {
        unsigned long long key = chk[t];
        int slot = 511 - (int)(key & 0xFFFFFFFFull);
        float m = keep[slot] ? bsc[slot] : -1.0f;
        bool ok = (m >= 0.5f);
        float* ob = out + ((size_t)img * POST + t) * 4;
        ob[0] = ok ? bx1[slot] : 0.f;
        ob[1] = ok ? by1[slot] : 0.f;
        ob[2] = ok ? bx2[slot] : 0.f;
        ob[3] = ok ? by2[slot] : 0.f;
        out[(size_t)BATCH * POST * 4 + img * POST + t] = ok ? m : 0.f;
    }
}

// ---------------- launcher ----------------
extern "C" void kernel_launch(void* const* d_in, const int* in_sizes, int n_in,
                              void* d_out, int out_size, void* d_ws, size_t ws_size,
                              hipStream_t stream) {
    const float* fm = (const float*)d_in[0];
    const float* w1 = (const float*)d_in[1];
    const float* b1 = (const float*)d_in[2];
    const float* w2 = (const float*)d_in[3];
    const float* b2 = (const float*)d_in[4];
    const float* w3 = (const float*)d_in[5];
    const float* b3 = (const float*)d_in[6];
    float* out = (float*)d_out;

    char* ws = (char*)d_ws;
    // ws layout (peak 16,637,184 B <= proven 18,087,936):
    //   w1pack @0        (9,437,184 B)  -- consumed by k_conv, then dead
    //   z      @0x900000 (7,200,000 B)  -- 16*2500*45 f32
    //   keys   @0        (2,883,584 B)  -- OVERLAYS w1pack (stream-ordered after k_conv)
    char* w1pack = ws;
    float* z = (float*)(ws + 0x900000);
    unsigned long long* keys = (unsigned long long*)ws;

    (void)hipMemsetAsync(z, 0, (size_t)BATCH * P_IMG * 45 * sizeof(float), stream);
    k_prepack<<<256, 256, 0, stream>>>(w1, w1pack);
    k_conv_mfma<<<BATCH * 20 * 4, 256, 0, stream>>>(fm, w1pack, b1, w2, w3, z);
    k_scores<<<(BATCH * NANCH + 255) / 256, 256, 0, stream>>>(z, b2, keys);
    k_sort_chunks<<<BATCH * NCHUNK, 512, 0, stream>>>(keys);
    k_nms<<<BATCH, 256, 0, stream>>>(keys, z, b3, out);
}